// Round 10
// baseline (140.647 us; speedup 1.0000x reference)
//
#include <hip/hip_runtime.h>

// Problem constants
#define NROWS 512          // N
#define FEAT  8192         // NUM_CHANNELS*4*4
#define BDIM  64
#define CDIM  16
#define MCOLS 1024         // BDIM*CDIM
#define OUTC  8256         // FEAT + BDIM
#define KSPLIT 8
#define KCHUNK (FEAT / KSPLIT)     // 1024
#define MSIZE  (NROWS * MCOLS)     // 524288 floats = 2 MB

typedef __bf16 bf16x8 __attribute__((ext_vector_type(8)));
typedef float  floatx4 __attribute__((ext_vector_type(4)));
typedef _Float16 half2 __attribute__((ext_vector_type(2)));

// pack two f32 -> bf16x2 dword by byte-select (RTZ): result = hi.bytes[3:2] | lo.bytes[3:2]
static __device__ __forceinline__ unsigned int pkbf(float lo, float hi) {
    return __builtin_amdgcn_perm(__builtin_bit_cast(unsigned int, hi),
                                 __builtin_bit_cast(unsigned int, lo), 0x07060302u);
}

// pack two f32 -> f16x2 (round-toward-zero), as raw dword
static __device__ __forceinline__ unsigned int pk2h(float a, float b) {
    return __builtin_bit_cast(unsigned int, __builtin_amdgcn_cvt_pkrtz(a, b));
}

// packed |a-b| on two f16 lanes: v_pk_add(neg) + v_and (sign strip)
static __device__ __forceinline__ half2 absdiff2(unsigned int a, unsigned int b) {
    half2 d = __builtin_bit_cast(half2, a) - __builtin_bit_cast(half2, b);
    return __builtin_bit_cast(half2, __builtin_bit_cast(unsigned int, d) & 0x7FFF7FFFu);
}

// ---------------------------------------------------------------------------
// k_gemm2: M = x @ T with in-register fp32->bf16 conversion (no xb/Tt).
// bf16 MFMA 16x16x32, 128x64 tile, 256 thr (4 waves 2x2), BK=64, split-K=8.
// grid = 4(mt) x 16(nt) x 8(ks) = 512 blocks -> 2 blocks/CU.
// LDS layout identical to R7 (verified): panel(rr,h) = (rr*2+h)*512 ushorts,
// within panel row r: slot s holds k-chunk c where s = (c&3) ^ ((r>>1)&3),
// h = c>>2. Fragment readers/epilogue verbatim R7.
// Staging is register-double-buffered: next iter's global loads issue after
// barrier 2 and fly under the MFMAs.
// ---------------------------------------------------------------------------
__global__ __launch_bounds__(256, 2) void k_gemm2(const float* __restrict__ x,
                                                  const float* __restrict__ T,
                                                  float* __restrict__ Mp) {
    __shared__ __align__(16) unsigned short ldsA[128 * 64];   // 16 KB, 16 panels
    __shared__ __align__(16) unsigned short ldsB[64 * 64];    // 8 KB, 8 panels
    int bid = blockIdx.x, t = threadIdx.x;
    int mt = bid & 3, nt = (bid >> 2) & 15, ks = bid >> 6;
    int m0 = mt * 128, n0 = nt * 64, kbase = ks * KCHUNK;
    int w = t >> 6, l = t & 63;

    // A staging: 4 chunks/thread. q = t + 256*i -> row = q>>3 (0..127), c = q&7.
    const float* gA[4];
    unsigned short* lA[4];
#pragma unroll
    for (int i = 0; i < 4; ++i) {
        int q = t + 256 * i, row = q >> 3, cc = q & 7;
        gA[i] = x + (size_t)(m0 + row) * FEAT + kbase + cc * 8;
        int r = row & 15;
        lA[i] = ldsA + (((row >> 4) * 2 + (cc >> 2)) * 512 + r * 32 +
                        (((cc & 3) ^ ((r >> 1) & 3)) * 8));
    }
    // B staging: 2 chunks/thread. nr = t&63, c = (t>>6) + 4*i. Chunk holds
    // T[k..k+8][n0+nr] (j-strided dword loads, lanes -> consecutive n).
    const float* gB[2];
    unsigned short* lB[2];
    int nr = t & 63;
#pragma unroll
    for (int i = 0; i < 2; ++i) {
        int cc = (t >> 6) + 4 * i;
        gB[i] = T + (size_t)(kbase + cc * 8) * MCOLS + n0 + nr;
        int r = nr & 15;
        lB[i] = ldsB + (((nr >> 4) * 2 + (cc >> 2)) * 512 + r * 32 +
                        (((cc & 3) ^ ((r >> 1) & 3)) * 8));
    }

    // compute-side pointers (verbatim R7)
    int wr = w >> 1, wc = w & 1, fm = l & 15, fq = l >> 4;
    int fo = fm * 32 + ((fq ^ ((fm >> 1) & 3)) * 8);
    const unsigned short* paB = ldsA + (wr * 8) * 512 + fo;
    const unsigned short* pbB = ldsB + (wc * 4) * 512 + fo;

    floatx4 acc[4][2] = {};
    float4 ra[4][2];
    float  rb[2][8];

    // preload iter 0
#pragma unroll
    for (int i = 0; i < 4; ++i) {
        ra[i][0] = *(const float4*)(gA[i]);
        ra[i][1] = *(const float4*)(gA[i] + 4);
        gA[i] += 64;
    }
#pragma unroll
    for (int i = 0; i < 2; ++i) {
#pragma unroll
        for (int j = 0; j < 8; ++j) rb[i][j] = gB[i][(size_t)j * MCOLS];
        gB[i] += (size_t)64 * MCOLS;
    }

    for (int kk = 0; kk < KCHUNK; kk += 64) {
        __syncthreads();                      // LDS free (prev iter consumed)
#pragma unroll
        for (int i = 0; i < 4; ++i)
            *(uint4*)lA[i] = make_uint4(pkbf(ra[i][0].x, ra[i][0].y),
                                        pkbf(ra[i][0].z, ra[i][0].w),
                                        pkbf(ra[i][1].x, ra[i][1].y),
                                        pkbf(ra[i][1].z, ra[i][1].w));
#pragma unroll
        for (int i = 0; i < 2; ++i)
            *(uint4*)lB[i] = make_uint4(pkbf(rb[i][0], rb[i][1]),
                                        pkbf(rb[i][2], rb[i][3]),
                                        pkbf(rb[i][4], rb[i][5]),
                                        pkbf(rb[i][6], rb[i][7]));
        __syncthreads();                      // LDS ready
        if (kk + 64 < KCHUNK) {               // prefetch next iter under MFMA
#pragma unroll
            for (int i = 0; i < 4; ++i) {
                ra[i][0] = *(const float4*)(gA[i]);
                ra[i][1] = *(const float4*)(gA[i] + 4);
                gA[i] += 64;
            }
#pragma unroll
            for (int i = 0; i < 2; ++i) {
#pragma unroll
                for (int j = 0; j < 8; ++j) rb[i][j] = gB[i][(size_t)j * MCOLS];
                gB[i] += (size_t)64 * MCOLS;
            }
        }
#pragma unroll
        for (int h = 0; h < 2; ++h) {
            bf16x8 af[4], bfr[2];
#pragma unroll
            for (int a = 0; a < 4; ++a) af[a]  = *(const bf16x8*)(paB + (a * 2 + h) * 512);
#pragma unroll
            for (int b = 0; b < 2; ++b) bfr[b] = *(const bf16x8*)(pbB + (b * 2 + h) * 512);
#pragma unroll
            for (int a = 0; a < 4; ++a)
#pragma unroll
                for (int b = 0; b < 2; ++b)
                    acc[a][b] = __builtin_amdgcn_mfma_f32_16x16x32_bf16(af[a], bfr[b], acc[a][b], 0, 0, 0);
        }
    }

    // epilogue (verbatim R7): D layout col = l&15, row = (l>>4)*4 + r
    float* outp = Mp + (size_t)ks * MSIZE;
    int gr0 = m0 + wr * 64, gc0 = n0 + wc * 32;
#pragma unroll
    for (int a = 0; a < 4; ++a)
#pragma unroll
        for (int r = 0; r < 4; ++r) {
            int row = gr0 + a * 16 + fq * 4 + r;
#pragma unroll
            for (int b = 0; b < 2; ++b)
                outp[(size_t)row * MCOLS + gc0 + b * 16 + fm] = acc[a][b][r];
        }
}

// ---------------------------------------------------------------------------
// k_pair2: x->out copy + o[i,b] = sum_j exp(-L1(M_i,M_j)) -> out[:, 8192:].
// Copy (33.6 MB HBM) overlaps the VALU-bound distance loop across waves.
// Pair part verbatim R9 (passed): split-K reduce fused into staging, M in
// LDS as packed f16x2 (stride 12 dwords), v_pk_add_f16 distance engine.
// 256 blocks x 512 thr: b = bid&63, itp = bid>>6; groups g = t>>8.
// ---------------------------------------------------------------------------
__global__ __launch_bounds__(512, 2) void k_pair2(const float* __restrict__ Mp,
                                                  const float* __restrict__ x,
                                                  float* __restrict__ out) {
    __shared__ __align__(16) unsigned int ldsMh[NROWS * 12];  // 24576 B
    __shared__ float partial[8][64];
    int bid = blockIdx.x, t = threadIdx.x;
    int b = bid & 63, itp = bid >> 6;

    // x -> out[:, :8192] copy: 1M float4 over 256 blocks
#pragma unroll
    for (int u = 0; u < 8; ++u) {
        int gid = bid * 4096 + u * 512 + t;
        float4 v = *(const float4*)(x + (size_t)gid * 4);
        int row = gid >> 11, col4 = gid & 2047;
        *(float4*)(out + (size_t)row * OUTC + col4 * 4) = v;
    }

#pragma unroll
    for (int p = 0; p < 4; ++p) {
        int idx = t + p * 512;                // 2048 float4-slots (512 j x 4)
        int j = idx >> 2, c4 = idx & 3;
        const float* base = Mp + (size_t)j * MCOLS + b * CDIM + c4 * 4;
        float4 s = *(const float4*)base;
#pragma unroll
        for (int k = 1; k < KSPLIT; ++k) {
            float4 v = *(const float4*)(base + (size_t)k * MSIZE);
            s.x += v.x; s.y += v.y; s.z += v.z; s.w += v.w;
        }
        uint2 wv;
        wv.x = pk2h(s.x, s.y);
        wv.y = pk2h(s.z, s.w);
        *(uint2*)&ldsMh[j * 12 + c4 * 2] = wv;
    }
    __syncthreads();

    int lane = t & 63, w = t >> 6, g = t >> 8, wg = (t >> 6) & 3;
    int i = (itp * 2 + g) * 64 + lane;
    uint4 miA = *(const uint4*)&ldsMh[i * 12];       // c0..7
    uint4 miB = *(const uint4*)&ldsMh[i * 12 + 4];   // c8..15

    float acc = 0.0f;
    for (int jj = wg * 128; jj < wg * 128 + 128; ++jj) {
        uint4 mjA = *(const uint4*)&ldsMh[jj * 12];
        uint4 mjB = *(const uint4*)&ldsMh[jj * 12 + 4];
        half2 sA = (absdiff2(miA.x, mjA.x) + absdiff2(miA.y, mjA.y)) +
                   (absdiff2(miA.z, mjA.z) + absdiff2(miA.w, mjA.w));
        half2 sB = (absdiff2(miB.x, mjB.x) + absdiff2(miB.y, mjB.y)) +
                   (absdiff2(miB.z, mjB.z) + absdiff2(miB.w, mjB.w));
        half2 s = sA + sB;
        float d = (float)s.x + (float)s.y;
        acc += __expf(-d);
    }
    partial[w][lane] = acc;
    __syncthreads();
    if ((t & 255) < 64) {
        int ii = (itp * 2 + g) * 64 + (t & 63);
        float o = partial[g * 4 + 0][t & 63] + partial[g * 4 + 1][t & 63] +
                  partial[g * 4 + 2][t & 63] + partial[g * 4 + 3][t & 63];
        out[(size_t)ii * OUTC + FEAT + b] = o;
    }
}

// ---------------------------------------------------------------------------
extern "C" void kernel_launch(void* const* d_in, const int* in_sizes, int n_in,
                              void* d_out, int out_size, void* d_ws, size_t ws_size,
                              hipStream_t stream) {
    const float* x = (const float*)d_in[0];      // (512, 8192)
    const float* T = (const float*)d_in[1];      // (8192, 1024)
    float* out = (float*)d_out;                  // (512, 8256)

    // ws layout: Mp 8x2MB = 16MB
    float* Mp = (float*)d_ws;

    k_gemm2<<<512, 256, 0, stream>>>(x, T, Mp);
    k_pair2<<<256, 512, 0, stream>>>(Mp, x, out);
}

// Round 11
// 136.069 us; speedup vs baseline: 1.0336x; 1.0336x over previous
//
#include <hip/hip_runtime.h>

// Problem constants
#define NROWS 512          // N
#define FEAT  8192         // NUM_CHANNELS*4*4
#define BDIM  64
#define CDIM  16
#define MCOLS 1024         // BDIM*CDIM
#define OUTC  8256         // FEAT + BDIM
#define KSPLIT 8
#define KCHUNK (FEAT / KSPLIT)     // 1024
#define MSIZE  (NROWS * MCOLS)     // 524288 floats = 2 MB

typedef __bf16 bf16x8 __attribute__((ext_vector_type(8)));
typedef float  floatx4 __attribute__((ext_vector_type(4)));

#define AS1 __attribute__((address_space(1)))
#define AS3 __attribute__((address_space(3)))

// async global->LDS, 16B per lane. LDS dest = wave-uniform base + lane*16.
static __device__ __forceinline__ void gload16(const void* g, void* l) {
    __builtin_amdgcn_global_load_lds((AS1 void*)(g), (AS3 void*)(l), 16, 0, 0);
}

static __device__ __forceinline__ unsigned short f2bf(float f) {
    unsigned int x = __builtin_bit_cast(unsigned int, f);
    unsigned int r = (x + 0x7FFFu + ((x >> 16) & 1u)) >> 16;   // RNE
    return (unsigned short)r;
}

// ---------------------------------------------------------------------------
// k_prep: 256 blocks x 512 thr.  (best measured: R7 @ 135.95 us)
//  (a) x fp32 -> bf16 xb + copy x into out[:, :8192]  (8 units x 512 float4)
//  (b) T (8192x1024 f32) -> Tt (1024x8192 bf16), 64x64 LDS tiles, 2 at a time
// ---------------------------------------------------------------------------
__global__ __launch_bounds__(512, 2) void k_prep(const float* __restrict__ x,
                                                 const float* __restrict__ T,
                                                 unsigned short* __restrict__ xb,
                                                 unsigned short* __restrict__ Tt,
                                                 float* __restrict__ out) {
    __shared__ __align__(16) float lds[2][64][65];   // +1 pad: 2-way only (free)
    int bid = blockIdx.x, t = threadIdx.x;
#pragma unroll
    for (int u = 0; u < 8; ++u) {
        int gid = bid * 4096 + u * 512 + t;          // float4 index, 1M total
        float4 v = *(const float4*)(x + (size_t)gid * 4);
        ushort4 uu;
        uu.x = f2bf(v.x); uu.y = f2bf(v.y); uu.z = f2bf(v.z); uu.w = f2bf(v.w);
        *(ushort4*)(xb + (size_t)gid * 4) = uu;
        int row = gid >> 11, col4 = gid & 2047;
        *(float4*)(out + (size_t)row * OUTC + col4 * 4) = v;
    }
    // T transpose: 2048 tiles of 64x64; 8 per block, 2 concurrently
    int sub = t >> 8, tt = t & 255;
    for (int u = 0; u < 4; ++u) {
        int tile = bid * 8 + u * 2 + sub;
        int kt = tile & 127, nt = tile >> 7;         // 128 k-tiles x 16 n-tiles
        __syncthreads();                              // protect prior reads
        int kk = tt >> 2, q = tt & 3;
#pragma unroll
        for (int p = 0; p < 4; ++p) {
            int c4 = q + p * 4;
            float4 v = *(const float4*)(T + (size_t)(kt * 64 + kk) * MCOLS + nt * 64 + c4 * 4);
            lds[sub][kk][c4 * 4 + 0] = v.x; lds[sub][kk][c4 * 4 + 1] = v.y;
            lds[sub][kk][c4 * 4 + 2] = v.z; lds[sub][kk][c4 * 4 + 3] = v.w;
        }
        __syncthreads();
        int nr = tt >> 2, ck = tt & 3;
        unsigned int wv[8];
#pragma unroll
        for (int j = 0; j < 8; ++j) {
            unsigned int lo = f2bf(lds[sub][ck * 16 + j * 2 + 0][nr]);
            unsigned int hi = f2bf(lds[sub][ck * 16 + j * 2 + 1][nr]);
            wv[j] = lo | (hi << 16);
        }
        uint4* dst = (uint4*)(Tt + (size_t)(nt * 64 + nr) * FEAT + kt * 64 + ck * 16);
        dst[0] = make_uint4(wv[0], wv[1], wv[2], wv[3]);
        dst[1] = make_uint4(wv[4], wv[5], wv[6], wv[7]);
    }
}

// ---------------------------------------------------------------------------
// k_gemm: M = x@T, bf16 MFMA 16x16x32. 128x64 tile, 256 thr (4 waves, 2x2),
// BK=64 (16 K-iters), global_load_lds with XOR-swizzled chunks. split-K=8.
// grid = 4(mt) x 16(nt) x 8(ks) = 512 blocks -> exactly 2 blocks/CU so a
// second block computes while the first drains vmcnt at its barrier.
// ---------------------------------------------------------------------------
__global__ __launch_bounds__(256, 2) void k_gemm(const unsigned short* __restrict__ xb,
                                                 const unsigned short* __restrict__ Tt,
                                                 float* __restrict__ Mp) {
    __shared__ __align__(16) unsigned short ldsA[128 * 64];   // 16 KB, 16 panels
    __shared__ __align__(16) unsigned short ldsB[64 * 64];    // 8 KB, 8 panels
    int bid = blockIdx.x, t = threadIdx.x;
    int mt = bid & 3, nt = (bid >> 2) & 15, ks = bid >> 6;
    int m0 = mt * 128, n0 = nt * 64, kbase = ks * KCHUNK;
    int w = t >> 6, l = t & 63;

    int c  = (l & 3) ^ ((l >> 3) & 3);
    int lr = l >> 2;
    const unsigned short* gA0 = xb + (size_t)(m0 + w * 32 + lr) * FEAT + kbase + c * 8;
    const unsigned short* gA1 = gA0 + (size_t)16 * FEAT;
    const unsigned short* gB0 = Tt + (size_t)(n0 + w * 16 + lr) * FEAT + kbase + c * 8;
    unsigned short* lA00 = ldsA + (4 * w + 0) * 512;
    unsigned short* lA01 = ldsA + (4 * w + 1) * 512;
    unsigned short* lA10 = ldsA + (4 * w + 2) * 512;
    unsigned short* lA11 = ldsA + (4 * w + 3) * 512;
    unsigned short* lB0  = ldsB + (2 * w + 0) * 512;
    unsigned short* lB1  = ldsB + (2 * w + 1) * 512;

    int wr = w >> 1, wc = w & 1, fm = l & 15, fq = l >> 4;
    int fo = fm * 32 + ((fq ^ ((fm >> 1) & 3)) * 8);
    const unsigned short* paB = ldsA + (wr * 8) * 512 + fo;
    const unsigned short* pbB = ldsB + (wc * 4) * 512 + fo;

    floatx4 acc[4][2] = {};

    for (int kk = 0; kk < KCHUNK; kk += 64) {
        __syncthreads();                      // protect LDS from overwrite
        gload16(gA0 + kk,      lA00);
        gload16(gA0 + kk + 32, lA01);
        gload16(gA1 + kk,      lA10);
        gload16(gA1 + kk + 32, lA11);
        gload16(gB0 + kk,      lB0);
        gload16(gB0 + kk + 32, lB1);
        __syncthreads();                      // drains vmcnt -> LDS visible
#pragma unroll
        for (int h = 0; h < 2; ++h) {
            bf16x8 af[4], bfr[2];
#pragma unroll
            for (int a = 0; a < 4; ++a) af[a]  = *(const bf16x8*)(paB + (a * 2 + h) * 512);
#pragma unroll
            for (int b = 0; b < 2; ++b) bfr[b] = *(const bf16x8*)(pbB + (b * 2 + h) * 512);
#pragma unroll
            for (int a = 0; a < 4; ++a)
#pragma unroll
                for (int b = 0; b < 2; ++b)
                    acc[a][b] = __builtin_amdgcn_mfma_f32_16x16x32_bf16(af[a], bfr[b], acc[a][b], 0, 0, 0);
        }
    }

    // epilogue: D layout col = l&15, row = (l>>4)*4 + r
    float* outp = Mp + (size_t)ks * MSIZE;
    int gr0 = m0 + wr * 64, gc0 = n0 + wc * 32;
#pragma unroll
    for (int a = 0; a < 4; ++a)
#pragma unroll
        for (int r = 0; r < 4; ++r) {
            int row = gr0 + a * 16 + fq * 4 + r;
#pragma unroll
            for (int b = 0; b < 2; ++b)
                outp[(size_t)row * MCOLS + gc0 + b * 16 + fm] = acc[a][b][r];
        }
}

// ---------------------------------------------------------------------------
// k_pair: o[i,b] = sum_j exp(-L1(M_i,M_j)) -> out[:, 8192:8256].
// Split-K reduction fused into LDS staging (reads 8 Mp partials, LLC-hot).
// 256 blocks: b = bid&63, itp = bid>>6. Groups g = t>>8 handle it = itp*2+g;
// within a group 4 waves split j. j wave-uniform -> LDS broadcast reads.
// ---------------------------------------------------------------------------
__global__ __launch_bounds__(512, 2) void k_pair(const float* __restrict__ Mp,
                                                 float* __restrict__ out) {
    __shared__ float ldsM[NROWS * 20];                  // 40960 B, padded rows
    __shared__ float partial[8][64];
    int bid = blockIdx.x, t = threadIdx.x;
    int b = bid & 63, itp = bid >> 6;
#pragma unroll
    for (int p = 0; p < 4; ++p) {
        int idx = t + p * 512;                // 2048 float4 total
        int j = idx >> 2, c4 = idx & 3;
        const float* base = Mp + (size_t)j * MCOLS + b * CDIM + c4 * 4;
        float4 s = *(const float4*)base;
#pragma unroll
        for (int k = 1; k < KSPLIT; ++k) {
            float4 v = *(const float4*)(base + (size_t)k * MSIZE);
            s.x += v.x; s.y += v.y; s.z += v.z; s.w += v.w;
        }
        *(float4*)&ldsM[j * 20 + c4 * 4] = s;
    }
    __syncthreads();

    int lane = t & 63, w = t >> 6, g = t >> 8, wg = (t >> 6) & 3;
    int i = (itp * 2 + g) * 64 + lane;
    float mi[CDIM];
#pragma unroll
    for (int cc = 0; cc < CDIM; ++cc) mi[cc] = ldsM[i * 20 + cc];

    float acc = 0.0f;
    for (int jj = wg * 128; jj < wg * 128 + 128; ++jj) {
        float d = 0.0f;
#pragma unroll
        for (int cc = 0; cc < CDIM; ++cc) d += fabsf(mi[cc] - ldsM[jj * 20 + cc]);
        acc += __expf(-d);
    }
    partial[w][lane] = acc;
    __syncthreads();
    if ((t & 255) < 64) {
        int ii = (itp * 2 + g) * 64 + (t & 63);
        float o = partial[g * 4 + 0][t & 63] + partial[g * 4 + 1][t & 63] +
                  partial[g * 4 + 2][t & 63] + partial[g * 4 + 3][t & 63];
        out[(size_t)ii * OUTC + FEAT + b] = o;
    }
}

// ---------------------------------------------------------------------------
extern "C" void kernel_launch(void* const* d_in, const int* in_sizes, int n_in,
                              void* d_out, int out_size, void* d_ws, size_t ws_size,
                              hipStream_t stream) {
    const float* x = (const float*)d_in[0];      // (512, 8192)
    const float* T = (const float*)d_in[1];      // (8192, 1024)
    float* out = (float*)d_out;                  // (512, 8256)

    // ws layout: xb 8MB | Tt 16MB | Mp 8x2MB=16MB  (40MB total)
    unsigned short* xb = (unsigned short*)d_ws;
    unsigned short* Tt = (unsigned short*)((char*)d_ws + (8u << 20));
    float*          Mp = (float*)((char*)d_ws + (24u << 20));

    k_prep<<<256, 512, 0, stream>>>(x, T, xb, Tt, out);
    k_gemm<<<512, 256, 0, stream>>>(xb, Tt, Mp);
    k_pair<<<256, 512, 0, stream>>>(Mp, out);
}